// Round 10
// baseline (806.939 us; speedup 1.0000x reference)
//
#include <hip/hip_runtime.h>
#include <type_traits>

// GraphSAGE 3-layer + BN(train stats) + ReLU + classifier, MI355X.
// R10: unroll-8 gathers (8 rows in flight/wave), bn3+classifier fused into
//      one thread-per-row kernel (kills classifier GEMM + one h3 pass),
//      bucket_offsets parallelized (1024 thr, 4-way g-split), stats memset
//      folded into conv_all. GEMM (R9 512-thr pipelined) unchanged.

#define DEV static __device__ __forceinline__

typedef unsigned short us;
typedef __attribute__((ext_vector_type(8))) __bf16 bf16x8;
typedef __attribute__((ext_vector_type(4))) float f32x4;

DEV float bf2f(us u) { return __uint_as_float(((unsigned)u) << 16); }
DEV us f2bf(float f) {
    unsigned u = __float_as_uint(f);
    unsigned r = u + 0x7fffu + ((u >> 16) & 1u);  // round-nearest-even
    return (us)(r >> 16);
}
DEV void acc2(float* a, unsigned u) {
    a[0] += __uint_as_float(u << 16);
    a[1] += __uint_as_float(u & 0xffff0000u);
}

typedef __attribute__((address_space(3))) void lds_void;
typedef const __attribute__((address_space(1))) void gbl_void;
DEV void gll16(const void* g, void* l) {
    __builtin_amdgcn_global_load_lds((gbl_void*)g, (lds_void*)l, 16, 0, 0);
}

DEV bool is_i64(const int* ei) {
    return (ei[1] == 0) & (ei[3] == 0) & (ei[5] == 0) & (ei[7] == 0);
}

// ---------------- CSR build (bucketed two-level) ----------------

__global__ void bucket_hist(const int* __restrict__ ei, int E, int* __restrict__ hist2,
                            int NB, int chunk) {
    __shared__ int h[256];
    const int g = blockIdx.x, t = threadIdx.x;
    const bool i64 = is_i64(ei);
    h[t] = 0;
    __syncthreads();
    int beg = g * chunk, end = min(beg + chunk, E);
    for (int e = beg + t; e < end; e += 256) {
        int d = i64 ? ei[2 * (E + e)] : ei[E + e];
        atomicAdd(&h[d >> 9], 1);
    }
    __syncthreads();
    if (t < NB) hist2[g * NB + t] = h[t];
}

// 1024 threads: 4 threads per bucket, each owns 64 of the G=256 chunks.
__global__ void bucket_offsets(int* __restrict__ hist2, int* __restrict__ bucketBase,
                               int* __restrict__ rp, int N, int G, int NB) {
    __shared__ int part[1024];
    __shared__ int tot[256];
    const int t = threadIdx.x;
    const int b = t & 255, q = t >> 8;
    int sum = 0;
    if (b < NB)
        for (int g = q * 64; g < q * 64 + 64; ++g) sum += hist2[g * NB + b];
    part[q * 256 + b] = sum;
    __syncthreads();
    if (t < 256)
        tot[t] = part[t] + part[256 + t] + part[512 + t] + part[768 + t];
    __syncthreads();
    for (int off = 1; off < 256; off <<= 1) {
        int v = 0;
        if (t < 256 && t >= off) v = tot[t - off];
        __syncthreads();
        if (t < 256) tot[t] += v;
        __syncthreads();
    }
    if (b < NB) {
        int sumb = part[b] + part[256 + b] + part[512 + b] + part[768 + b];
        int base = tot[b] - sumb;  // exclusive bucket base
        if (q == 0) {
            bucketBase[b] = base;
            if (b == NB - 1) {
                bucketBase[NB] = tot[b];
                rp[N] = tot[b];
            }
        }
        int run = base;
        for (int qq = 0; qq < q; ++qq) run += part[qq * 256 + b];
        for (int g = q * 64; g < q * 64 + 64; ++g) {
            int v = hist2[g * NB + b];
            hist2[g * NB + b] = run;
            run += v;
        }
    }
}

__global__ void scatter8(const int* __restrict__ ei, int E, const int* __restrict__ hist2,
                         uint2* __restrict__ ebuf, int NB, int chunk) {
    __shared__ int off[256];
    const int g = blockIdx.x, t = threadIdx.x;
    const bool i64 = is_i64(ei);
    if (t < NB) off[t] = hist2[g * NB + t];
    __syncthreads();
    int beg = g * chunk, end = min(beg + chunk, E);
    for (int e = beg + t; e < end; e += 256) {
        int s = i64 ? ei[2 * e] : ei[e];
        int d = i64 ? ei[2 * (E + e)] : ei[E + e];
        int p = atomicAdd(&off[d >> 9], 1);
        ebuf[p] = make_uint2((unsigned)s, (unsigned)d);
    }
}

__global__ void fine_csr(const uint2* __restrict__ ebuf, const int* __restrict__ bucketBase,
                         int N, int* __restrict__ rp, int* __restrict__ csr) {
    __shared__ int cnt[512];
    __shared__ int red[256];
    const int b = blockIdx.x, t = threadIdx.x;
    const int node0 = b << 9;
    cnt[t] = 0;
    cnt[t + 256] = 0;
    __syncthreads();
    const int ebeg = bucketBase[b], eend = bucketBase[b + 1];
    for (int e = ebeg + t; e < eend; e += 256) {
        uint2 r = ebuf[e];
        atomicAdd(&cnt[r.y & 511], 1);
    }
    __syncthreads();
    int c0 = cnt[2 * t], c1 = cnt[2 * t + 1];
    int s = c0 + c1;
    red[t] = s;
    __syncthreads();
    for (int off = 1; off < 256; off <<= 1) {
        int v = (t >= off) ? red[t - off] : 0;
        __syncthreads();
        red[t] += v;
        __syncthreads();
    }
    int pre = red[t] - s;
    int n0 = node0 + 2 * t;
    if (n0 < N) rp[n0] = ebeg + pre;
    if (n0 + 1 < N) rp[n0 + 1] = ebeg + pre + c0;
    __syncthreads();
    cnt[2 * t] = ebeg + pre;
    cnt[2 * t + 1] = ebeg + pre + c0;
    __syncthreads();
    for (int e = ebeg + t; e < eend; e += 256) {
        uint2 r = ebuf[e];
        int p = atomicAdd(&cnt[r.y & 511], 1);
        csr[p] = (int)r.x;
    }
}

// ---------------- f32 -> bf16 conversion (x + weights) + stats zeroing ----

struct WSeg { const float* s; us* d; int n4; int l2w4; int stride; };
struct WConvAll { WSeg seg[8]; };

__global__ void conv_all(WConvAll wc, float* __restrict__ stats, int nstats) {
    if (blockIdx.x == 0) {
        for (int i = threadIdx.x; i < nstats; i += blockDim.x) stats[i] = 0.f;
    }
    for (int sg = 0; sg < 8; ++sg) {
        WSeg w = wc.seg[sg];
        for (int i = blockIdx.x * blockDim.x + threadIdx.x; i < w.n4; i += gridDim.x * blockDim.x) {
            float4 v = ((const float4*)w.s)[i];
            ushort4 r;
            r.x = f2bf(v.x); r.y = f2bf(v.y); r.z = f2bf(v.z); r.w = f2bf(v.w);
            int row = i >> w.l2w4;
            int col = (i - (row << w.l2w4)) * 4;
            *(ushort4*)(w.d + (size_t)row * w.stride + col) = r;
        }
    }
}

// ---------------- mean aggregation (wave per node, unroll-8) ----------------

template <int VEC>  // cols = 64*VEC
__global__ void agg_mean(const us* __restrict__ X, const int* __restrict__ rp,
                         const int* __restrict__ csr, us* __restrict__ M, int n) {
    const int cols = VEC * 64;
    int w = blockIdx.x * (blockDim.x >> 6) + (threadIdx.x >> 6);
    int lane = threadIdx.x & 63;
    if (w >= n) return;
    int beg = rp[w], end = rp[w + 1];
    const us* Xb = X + lane * VEC;
    using LT = typename std::conditional<VEC == 2, unsigned, uint2>::type;
    float acc[VEC] = {};
    int e = beg;
    for (; e + 8 <= end; e += 8) {
        int j[8];
#pragma unroll
        for (int u = 0; u < 8; ++u) j[u] = csr[e + u];
        LT v[8];
#pragma unroll
        for (int u = 0; u < 8; ++u) v[u] = *(const LT*)(Xb + (size_t)j[u] * cols);
#pragma unroll
        for (int u = 0; u < 8; ++u) {
            if (VEC == 2) {
                acc2(acc, *(const unsigned*)&v[u]);
            } else {
                const uint2* p = (const uint2*)&v[u];
                acc2(acc, p->x);
                acc2(acc + 2, p->y);
            }
        }
    }
    for (; e + 2 <= end; e += 2) {
        int j0 = csr[e], j1 = csr[e + 1];
        LT v0 = *(const LT*)(Xb + (size_t)j0 * cols);
        LT v1 = *(const LT*)(Xb + (size_t)j1 * cols);
        if (VEC == 2) {
            acc2(acc, *(const unsigned*)&v0);
            acc2(acc, *(const unsigned*)&v1);
        } else {
            const uint2* p0 = (const uint2*)&v0;
            const uint2* p1 = (const uint2*)&v1;
            acc2(acc, p0->x); acc2(acc + 2, p0->y);
            acc2(acc, p1->x); acc2(acc + 2, p1->y);
        }
    }
    if (e < end) {
        LT v0 = *(const LT*)(Xb + (size_t)csr[e] * cols);
        if (VEC == 2) {
            acc2(acc, *(const unsigned*)&v0);
        } else {
            const uint2* p0 = (const uint2*)&v0;
            acc2(acc, p0->x); acc2(acc + 2, p0->y);
        }
    }
    float inv = 1.0f / (float)max(end - beg, 1);
    us* q = M + (size_t)w * cols + lane * VEC;
    if (VEC == 2) {
        *(ushort2*)q = make_ushort2(f2bf(acc[0] * inv), f2bf(acc[1] * inv));
    } else {
        *(ushort4*)q = make_ushort4(f2bf(acc[0] * inv), f2bf(acc[1] * inv),
                                    f2bf(acc[2] * inv), f2bf(acc[3] * inv));
    }
}

// layer-3 post-GEMM aggregation (unroll-8)
__global__ void agg_post(const us* __restrict__ Yc, const int* __restrict__ rp,
                         const int* __restrict__ csr, const float* __restrict__ bias,
                         us* __restrict__ H, int n) {
    int w = blockIdx.x * (blockDim.x >> 6) + (threadIdx.x >> 6);
    int lane = threadIdx.x & 63;
    if (w >= n) return;
    int beg = rp[w], end = rp[w + 1];
    const us* Yb = Yc + lane * 2;
    float a[2] = {};
    int e = beg;
    for (; e + 8 <= end; e += 8) {
        int j[8];
#pragma unroll
        for (int u = 0; u < 8; ++u) j[u] = csr[e + u];
        unsigned v[8];
#pragma unroll
        for (int u = 0; u < 8; ++u) v[u] = *(const unsigned*)(Yb + (size_t)j[u] * 256);
#pragma unroll
        for (int u = 0; u < 8; ++u) acc2(a, v[u]);
    }
    for (; e + 2 <= end; e += 2) {
        unsigned v0 = *(const unsigned*)(Yb + (size_t)csr[e] * 256);
        unsigned v1 = *(const unsigned*)(Yb + (size_t)csr[e + 1] * 256);
        acc2(a, v0);
        acc2(a, v1);
    }
    if (e < end) acc2(a, *(const unsigned*)(Yb + (size_t)csr[e] * 256));
    float inv = 1.0f / (float)max(end - beg, 1);
    unsigned uz = *(const unsigned*)(Yc + (size_t)w * 256 + 128 + lane * 2);
    float2 bv = *(const float2*)(bias + lane * 2);
    float r0 = a[0] * inv + __uint_as_float(uz << 16) + bv.x;
    float r1 = a[1] * inv + __uint_as_float(uz & 0xffff0000u) + bv.y;
    *(ushort2*)(H + (size_t)w * 128 + lane * 2) = make_ushort2(f2bf(r0), f2bf(r1));
}

// ---------------- MFMA GEMM: distance-2 DMA pipeline, dual LDS buffers ----

template <int THREADS, int BM, int BN, int WM, int WN>
__launch_bounds__(THREADS)
__global__ void gemm_mfma(const us* __restrict__ A0, int K0,
                          const us* __restrict__ A1, int K1,
                          const us* __restrict__ W, const float* __restrict__ bias,
                          int n, int outc, us* __restrict__ Cbf, float* __restrict__ Cf,
                          float* __restrict__ st0, float* __restrict__ st1) {
    constexpr int MT = WM / 16;
    constexpr int NT = WN / 16;
    constexpr int WCols = BN / WN;
    constexpr int NDMA = (BM * 4 + BN * 4) / THREADS;
    static_assert((BM * 4) % THREADS == 0 && (BN * 4) % THREADS == 0, "uniform DMA");
    static_assert((BM / WM) * (BN / WN) == THREADS / 64, "wave tiling");
    __shared__ __align__(16) us As[2][BM * 32];
    __shared__ __align__(16) us Bs[2][BN * 32];
    __shared__ float colred[2][BN];

    const int t = threadIdx.x;
    const int wid = t >> 6, lane = t & 63;
    const int wr = wid / WCols, wcc = wid % WCols;
    const int row0 = blockIdx.x * BM;
    const int col0 = blockIdx.y * BN;
    const int Kp = K0 + K1;
    const int nk = Kp >> 5;
    const int l15 = lane & 15, l4 = lane >> 4;

    auto issue = [&](int kidx, int p) {
        int kc = kidx << 5;
        const us* A = (kc < K0) ? A0 : A1;
        int rs = (kc < K0) ? K0 : K1;
        int ko = (kc < K0) ? kc : kc - K0;
#pragma unroll
        for (int c = t; c < BM * 4; c += THREADS) {
            int blk = c >> 6;
            int row = row0 + (blk << 4) + l15;
            gll16(A + (size_t)row * rs + ko + (l4 << 3), (char*)As[p] + blk * 1024 + lane * 16);
        }
#pragma unroll
        for (int c = t; c < BN * 4; c += THREADS) {
            int blk = c >> 6;
            int col = col0 + (blk << 4) + l15;
            gll16(W + (size_t)col * Kp + kc + (l4 << 3), (char*)Bs[p] + blk * 1024 + lane * 16);
        }
    };

    f32x4 acc[MT][NT];
#pragma unroll
    for (int i = 0; i < MT; ++i)
#pragma unroll
        for (int j = 0; j < NT; ++j) acc[i][j] = (f32x4){0.f, 0.f, 0.f, 0.f};

    issue(0, 0);
    if (nk > 1) issue(1, 1);
    for (int k = 0; k < nk; ++k) {
        if (k + 1 < nk) asm volatile("s_waitcnt vmcnt(%0)" :: "i"(NDMA) : "memory");
        else            asm volatile("s_waitcnt vmcnt(0)" ::: "memory");
        asm volatile("s_barrier" ::: "memory");
        const int p = k & 1;
        bf16x8 af[MT], bfr[NT];
#pragma unroll
        for (int mt = 0; mt < MT; ++mt)
            af[mt] = *(const bf16x8*)((char*)As[p] + (wr * MT + mt) * 1024 + lane * 16);
#pragma unroll
        for (int nt = 0; nt < NT; ++nt)
            bfr[nt] = *(const bf16x8*)((char*)Bs[p] + (wcc * NT + nt) * 1024 + lane * 16);
#pragma unroll
        for (int mt = 0; mt < MT; ++mt)
#pragma unroll
            for (int nt = 0; nt < NT; ++nt)
                acc[mt][nt] = __builtin_amdgcn_mfma_f32_16x16x32_bf16(af[mt], bfr[nt], acc[mt][nt], 0, 0, 0);
        if (k + 2 < nk) {
            asm volatile("s_barrier" ::: "memory");
            issue(k + 2, p);
        }
    }

    if (st0) {
#pragma unroll
        for (int c = t; c < 2 * BN; c += THREADS) (&colred[0][0])[c] = 0.f;
        __syncthreads();
    }

    // epilogue: C/D map col=lane&15, row=(lane>>4)*4+reg
#pragma unroll
    for (int nt = 0; nt < NT; ++nt) {
        int col = col0 + wcc * WN + nt * 16 + l15;
        bool cok = col < outc;
        float bv = (bias != nullptr && cok) ? bias[col] : 0.f;
        float ls = 0.f, lq = 0.f;
#pragma unroll
        for (int mt = 0; mt < MT; ++mt) {
            int rbase = row0 + wr * WM + mt * 16 + (l4 << 2);
#pragma unroll
            for (int i = 0; i < 4; ++i) {
                int r = rbase + i;
                if (r < n && cok) {
                    float v = acc[mt][nt][i] + bv;
                    if (Cf) Cf[(size_t)r * outc + col] = v;
                    else Cbf[(size_t)r * outc + col] = f2bf(v);
                    ls += v;
                    lq += v * v;
                }
            }
        }
        if (st0 && cok) {
            int lc = wcc * WN + nt * 16 + l15;
            atomicAdd(&colred[0][lc], ls);
            atomicAdd(&colred[1][lc], lq);
        }
    }
    if (st0) {
        __syncthreads();
        int rep = (blockIdx.x & 7) << 8;
        for (int c = t; c < BN; c += THREADS) {
            if (col0 + c < outc) {
                atomicAdd(&st0[rep + col0 + c], colred[0][c]);
                atomicAdd(&st1[rep + col0 + c], colred[1][c]);
            }
        }
    }
}

// ---------------- BatchNorm ----------------

__global__ void bn_stats(const us* __restrict__ H, int n, int c,
                         float* __restrict__ s0, float* __restrict__ s1) {
    int col = threadIdx.x;
    if (col >= c) return;
    float s = 0.f, q = 0.f;
    for (int r = blockIdx.x; r < n; r += gridDim.x) {
        float v = bf2f(H[(size_t)r * c + col]);
        s += v;
        q += v * v;
    }
    int rep = (blockIdx.x & 7) << 8;
    atomicAdd(&s0[rep + col], s);
    atomicAdd(&s1[rep + col], q);
}

// bn_apply with inline finalize (sums 8 stat replicas).
__global__ void bn_apply(us* __restrict__ H, int n8, int c,
                         const float* __restrict__ s0, const float* __restrict__ s1,
                         const float* __restrict__ g, const float* __restrict__ be, float fn) {
    __shared__ float sc[256], sh[256];
    int t = threadIdx.x;
    if (t < c) {
        float s = 0.f, q = 0.f;
#pragma unroll
        for (int r = 0; r < 8; ++r) {
            s += s0[(r << 8) + t];
            q += s1[(r << 8) + t];
        }
        float mean = s / fn;
        float var = q / fn - mean * mean;
        float scale = g[t] * rsqrtf(var + 1e-5f);
        sc[t] = scale;
        sh[t] = be[t] - mean * scale;
    }
    __syncthreads();
    int cdiv8 = c >> 3;
    for (int i = blockIdx.x * blockDim.x + t; i < n8; i += gridDim.x * blockDim.x) {
        int col = (i % cdiv8) << 3;
        uint4 v = ((const uint4*)H)[i];
        float f[8];
        f[0] = __uint_as_float(v.x << 16); f[1] = __uint_as_float(v.x & 0xffff0000u);
        f[2] = __uint_as_float(v.y << 16); f[3] = __uint_as_float(v.y & 0xffff0000u);
        f[4] = __uint_as_float(v.z << 16); f[5] = __uint_as_float(v.z & 0xffff0000u);
        f[6] = __uint_as_float(v.w << 16); f[7] = __uint_as_float(v.w & 0xffff0000u);
        float4 sc0 = *(const float4*)&sc[col];
        float4 sc1 = *(const float4*)&sc[col + 4];
        float4 sh0 = *(const float4*)&sh[col];
        float4 sh1 = *(const float4*)&sh[col + 4];
        f[0] = fmaxf(f[0] * sc0.x + sh0.x, 0.f);
        f[1] = fmaxf(f[1] * sc0.y + sh0.y, 0.f);
        f[2] = fmaxf(f[2] * sc0.z + sh0.z, 0.f);
        f[3] = fmaxf(f[3] * sc0.w + sh0.w, 0.f);
        f[4] = fmaxf(f[4] * sc1.x + sh1.x, 0.f);
        f[5] = fmaxf(f[5] * sc1.y + sh1.y, 0.f);
        f[6] = fmaxf(f[6] * sc1.z + sh1.z, 0.f);
        f[7] = fmaxf(f[7] * sc1.w + sh1.w, 0.f);
        uint4 o;
        o.x = (unsigned)f2bf(f[0]) | ((unsigned)f2bf(f[1]) << 16);
        o.y = (unsigned)f2bf(f[2]) | ((unsigned)f2bf(f[3]) << 16);
        o.z = (unsigned)f2bf(f[4]) | ((unsigned)f2bf(f[5]) << 16);
        o.w = (unsigned)f2bf(f[6]) | ((unsigned)f2bf(f[7]) << 16);
        ((uint4*)H)[i] = o;
    }
}

// ---------------- fused bn3 + classifier: out = relu(bn3(h3)) @ wc^T + bc ----
// thread-per-row; wc (15x128) in LDS as f32; bn scale/shift from 8 replicas.

__global__ void cls_fused(const us* __restrict__ H, int n,
                          const float* __restrict__ s0, const float* __restrict__ s1,
                          const float* __restrict__ g, const float* __restrict__ be, float fn,
                          const us* __restrict__ wcb, const float* __restrict__ bc,
                          float* __restrict__ out) {
    __shared__ float sc[128], sh[128], wl[15][128], bcs[15];
    int t = threadIdx.x;
    if (t < 128) {
        float s = 0.f, q = 0.f;
#pragma unroll
        for (int r = 0; r < 8; ++r) {
            s += s0[(r << 8) + t];
            q += s1[(r << 8) + t];
        }
        float mean = s / fn;
        float var = q / fn - mean * mean;
        float scale = g[t] * rsqrtf(var + 1e-5f);
        sc[t] = scale;
        sh[t] = be[t] - mean * scale;
    }
    for (int i = t; i < 15 * 128; i += blockDim.x) wl[i >> 7][i & 127] = bf2f(wcb[i]);
    if (t < 15) bcs[t] = bc[t];
    __syncthreads();
    for (int r = blockIdx.x * blockDim.x + t; r < n; r += gridDim.x * blockDim.x) {
        const uint4* hp = (const uint4*)(H + (size_t)r * 128);
        float acc[15] = {};
#pragma unroll
        for (int k8 = 0; k8 < 16; ++k8) {
            uint4 v = hp[k8];
            float f[8];
            f[0] = __uint_as_float(v.x << 16); f[1] = __uint_as_float(v.x & 0xffff0000u);
            f[2] = __uint_as_float(v.y << 16); f[3] = __uint_as_float(v.y & 0xffff0000u);
            f[4] = __uint_as_float(v.z << 16); f[5] = __uint_as_float(v.z & 0xffff0000u);
            f[6] = __uint_as_float(v.w << 16); f[7] = __uint_as_float(v.w & 0xffff0000u);
            int kb = k8 << 3;
#pragma unroll
            for (int j = 0; j < 8; ++j) {
                float hv = fmaxf(f[j] * sc[kb + j] + sh[kb + j], 0.f);
#pragma unroll
                for (int c = 0; c < 15; ++c) acc[c] += hv * wl[c][kb + j];
            }
        }
        float* op = out + (size_t)r * 15;
#pragma unroll
        for (int c = 0; c < 15; ++c) op[c] = acc[c] + bcs[c];
    }
}

// ---------------- host ----------------

extern "C" void kernel_launch(void* const* d_in, const int* in_sizes, int n_in,
                              void* d_out, int out_size, void* d_ws, size_t ws_size,
                              hipStream_t stream) {
    const float* x = (const float*)d_in[0];
    const int* ei = (const int*)d_in[1];
    const float* w1_l = (const float*)d_in[2];
    const float* b1_l = (const float*)d_in[3];
    const float* w1_r = (const float*)d_in[4];
    const float* g1 = (const float*)d_in[5];
    const float* be1 = (const float*)d_in[6];
    const float* w2_l = (const float*)d_in[7];
    const float* b2_l = (const float*)d_in[8];
    const float* w2_r = (const float*)d_in[9];
    const float* g2 = (const float*)d_in[10];
    const float* be2 = (const float*)d_in[11];
    const float* w3_l = (const float*)d_in[12];
    const float* b3_l = (const float*)d_in[13];
    const float* w3_r = (const float*)d_in[14];
    const float* g3 = (const float*)d_in[15];
    const float* be3 = (const float*)d_in[16];
    const float* wcf = (const float*)d_in[17];
    const float* bc = (const float*)d_in[18];

    const int N = in_sizes[0] / 128;
    const int E = in_sizes[1] / 2;
    const int NB = (N + 511) >> 9;
    const int G = 256;
    const int chunk = (E + G - 1) / G;

    char* ws = (char*)d_ws;
    size_t off = 0;
    auto alloc = [&](size_t bytes) -> char* {
        char* p = ws + off;
        off += (bytes + 255) & ~(size_t)255;
        return p;
    };
    int* rp = (int*)alloc((size_t)(N + 1) * 4);
    int* csr = (int*)alloc((size_t)E * 4);
    int* hist2 = (int*)alloc((size_t)G * NB * 4);
    int* bucketBase = (int*)alloc((size_t)(NB + 1) * 4);
    uint2* ebuf = (uint2*)alloc((size_t)E * 8);
    us* xbf = (us*)alloc((size_t)N * 128 * 2);
    us* M = (us*)alloc((size_t)N * 256 * 2);   // gather out / Yc
    us* Ha = (us*)alloc((size_t)N * 256 * 2);  // h1; later h3
    us* Hb = (us*)alloc((size_t)N * 256 * 2);  // h2
    float* stats = (float*)alloc(6 * 8 * 256 * 4);
    float* s01 = stats,          *s11 = stats + 2048;
    float* s02 = stats + 4096,   *s12 = stats + 6144;
    float* s03 = stats + 8192,   *s13 = stats + 10240;
    us* wcat1 = (us*)alloc(256 * 256 * 2);     // [256][128+128] = [w1_l | w1_r]
    us* wcat2 = (us*)alloc(256 * 512 * 2);     // [256][256+256] = [w2_l | w2_r]
    us* w3cat = (us*)alloc(256 * 256 * 2);     // rows 0-127 w3_l, 128-255 w3_r
    us* wc_b = (us*)alloc(16 * 128 * 2);
    alloc(1 << 20);                             // pad: absorbs OOB staging reads
    (void)ws_size; (void)n_in; (void)out_size;

    // --- conversions (+stats zero) + CSR build ---
    WConvAll wc;
    wc.seg[0] = {x,    xbf,         N * 128 / 4,  5, 128};
    wc.seg[1] = {w1_l, wcat1,       256 * 128 / 4, 5, 256};
    wc.seg[2] = {w1_r, wcat1 + 128, 256 * 128 / 4, 5, 256};
    wc.seg[3] = {w2_l, wcat2,       256 * 256 / 4, 6, 512};
    wc.seg[4] = {w2_r, wcat2 + 256, 256 * 256 / 4, 6, 512};
    wc.seg[5] = {w3_l, w3cat,             128 * 256 / 4, 6, 256};
    wc.seg[6] = {w3_r, w3cat + 128 * 256, 128 * 256 / 4, 6, 256};
    wc.seg[7] = {wcf,  wc_b,        15 * 128 / 4,  5, 128};
    conv_all<<<1024, 256, 0, stream>>>(wc, stats, 6 * 8 * 256);
    bucket_hist<<<G, 256, 0, stream>>>(ei, E, hist2, NB, chunk);
    bucket_offsets<<<1, 1024, 0, stream>>>(hist2, bucketBase, rp, N, G, NB);
    scatter8<<<G, 256, 0, stream>>>(ei, E, hist2, ebuf, NB, chunk);
    fine_csr<<<NB, 256, 0, stream>>>(ebuf, bucketBase, N, rp, csr);

    const int aggGrid = (N + 3) / 4;
    const int rowTiles = (N + 127) / 128;

    // --- layer 1: 128 -> 256 (stats fused) ---
    agg_mean<2><<<aggGrid, 256, 0, stream>>>(xbf, rp, csr, M, N);
    gemm_mfma<512, 128, 256, 64, 64><<<rowTiles, 512, 0, stream>>>(
        M, 128, xbf, 128, wcat1, b1_l, N, 256, Ha, nullptr, s01, s11);
    bn_apply<<<2048, 256, 0, stream>>>(Ha, N * 256 / 8, 256, s01, s11, g1, be1, (float)N);

    // --- layer 2: 256 -> 256 (stats fused) ---
    agg_mean<4><<<aggGrid, 256, 0, stream>>>(Ha, rp, csr, M, N);
    gemm_mfma<512, 128, 256, 64, 64><<<rowTiles, 512, 0, stream>>>(
        M, 256, Ha, 256, wcat2, b2_l, N, 256, Hb, nullptr, s02, s12);
    bn_apply<<<2048, 256, 0, stream>>>(Hb, N * 256 / 8, 256, s02, s12, g2, be2, (float)N);

    // --- layer 3: GEMM-first: [Y|Z] = Hb @ [w3l;w3r]^T, aggregate 128 cols ---
    gemm_mfma<512, 128, 256, 64, 64><<<rowTiles, 512, 0, stream>>>(
        Hb, 256, nullptr, 0, w3cat, nullptr, N, 256, M, nullptr, nullptr, nullptr);
    agg_post<<<aggGrid, 256, 0, stream>>>(M, rp, csr, b3_l, Ha, N);
    bn_stats<<<1024, 256, 0, stream>>>(Ha, N, 128, s03, s13);

    // --- fused bn3 + classifier -> f32 d_out ---
    cls_fused<<<512, 256, 0, stream>>>(Ha, N, s03, s13, g3, be3, (float)N, wc_b, bc,
                                       (float*)d_out);
}